// Round 10
// baseline (388.492 us; speedup 1.0000x reference)
//
#include <hip/hip_runtime.h>
#include <hip/hip_bf16.h>
#include <math.h>

#define NN 50000      // nodes
#define NE 500000     // edges (before self loops)
#define NP 10000      // pairs
#define FIN 128
#define HD 256
#define NE_TOT (NE + NN)   // with self loops

typedef __attribute__((ext_vector_type(8))) short bf16x8;
typedef __attribute__((ext_vector_type(4))) float f32x4;
typedef __attribute__((ext_vector_type(2))) float f32x2;

// round-to-nearest-even fp32 -> bf16 bits
__device__ inline unsigned short f2bf(float f) {
  unsigned int u = __float_as_uint(f);
  unsigned int r = (u + 0x7fffu + ((u >> 16) & 1u)) >> 16;
  return (unsigned short)r;
}

__device__ inline float bflo(unsigned int u) { return __uint_as_float(u << 16); }
__device__ inline float bfhi(unsigned int u) { return __uint_as_float(u & 0xffff0000u); }

// fp8 e4m3 encode (HW, RNE): one float -> one byte
__device__ inline unsigned char f2fp8(float v) {
  int pk = __builtin_amdgcn_cvt_pk_fp8_f32(v, v, 0, false);
  return (unsigned char)(pk & 0xff);
}

// ---------------- merged init: deg=1, flags=0, cnt=0, weight transpose+convert ----------------
// MUST be launched with >= max(NN, FIN*HD) threads (196 blocks x 256 = 50176).
__global__ void init_prep(int* __restrict__ deg, int* __restrict__ flags, int* __restrict__ node_cnt,
                          const float* __restrict__ W1, const float* __restrict__ W2,
                          unsigned short* __restrict__ W1T, unsigned short* __restrict__ W2T) {
  int idx = blockIdx.x * 256 + threadIdx.x;
  if (idx < NN) { deg[idx] = 1; flags[idx] = 0; }
  if (idx == 0) *node_cnt = 0;
  if (idx < FIN * HD) {
    int n = idx / FIN, k = idx - n * FIN;
    W1T[idx] = f2bf(W1[(size_t)k * HD + n]);
    int n2 = idx / HD, k2 = idx - n2 * HD;
    W2T[idx] = f2bf(W2[(size_t)k2 * FIN + n2]);
  }
}

// ---------------- merged histogram + mask-flag ----------------
__global__ void hist_flag(const int* __restrict__ dst, int* __restrict__ deg,
                          const int* __restrict__ mask, int* __restrict__ flags) {
  int e = blockIdx.x * blockDim.x + threadIdx.x;
  if (e < NE) atomicAdd(&deg[dst[e]], 1);
  else if (e < NE + 2 * NP) flags[mask[e - NE]] = 1;
}

// ---------------- single-block scan (row_ptr/cursor) + compact (node_list) ----------------
__global__ __launch_bounds__(1024)
void scan_compact(const int* __restrict__ deg, int* __restrict__ row_ptr,
                  int* __restrict__ cursor, const int* __restrict__ flags,
                  int* __restrict__ node_list, int* __restrict__ node_cnt) {
  constexpr int T = 1024;
  constexpr int CH = (NN + T - 1) / T;  // 49
  __shared__ int part[T];
  int t = threadIdx.x;
  int lo = t * CH, hi = min(lo + CH, NN);
  int sum = 0;
  for (int i = lo; i < hi; i++) sum += deg[i];
  part[t] = sum;
  __syncthreads();
  for (int off = 1; off < T; off <<= 1) {
    int v = (t >= off) ? part[t - off] : 0;
    __syncthreads();
    part[t] += v;
    __syncthreads();
  }
  int run = part[t] - sum;  // exclusive prefix
  for (int i = lo; i < hi; i++) {
    row_ptr[i] = run;
    cursor[i] = run;
    run += deg[i];
  }
  if (t == T - 1) row_ptr[NN] = NE_TOT;
  // compact masked nodes
  for (int i = lo; i < hi; i++) {
    if (flags[i]) {
      int p = atomicAdd(node_cnt, 1);
      node_list[p] = i;
    }
  }
}

__global__ void scatter_kernel(const int* __restrict__ src, const int* __restrict__ dst,
                               int* __restrict__ cursor, int* __restrict__ ssrc) {
  int e = blockIdx.x * blockDim.x + threadIdx.x;
  if (e < NE) {
    int pos = atomicAdd(&cursor[dst[e]], 1);
    ssrc[pos] = src[e];
  } else if (e < NE_TOT) {
    int i = e - NE;
    int pos = atomicAdd(&cursor[i], 1);
    ssrc[pos] = i;
  }
}

// ---------------- bf16 MFMA GEMM + fused es/ed epilogue (LDS reduce, plain store) ----------------
// C[M,BN] = A[M,KTOT] @ B[KTOT,BN]; BT is B^T bf16 [BN][KTOT].
// C stored fp8-e4m3 (C_FP8) or bf16. es/ed from fp32 accumulators (exact).
template <int BN, int KTOT, bool A_BF16, bool C_FP8>
__global__ __launch_bounds__(256)
void mfma_gemm(const void* __restrict__ Aptr, const unsigned short* __restrict__ BT,
               void* __restrict__ Cptr, const float* __restrict__ a_s,
               const float* __restrict__ a_d, float* __restrict__ es, float* __restrict__ ed,
               int M) {
  constexpr int LDK = 72;
  constexpr int CN = BN / 2;   // cols per wave
  constexpr int NT = CN / 16;  // 16x16 col tiles per wave
  __shared__ unsigned short As[64][LDK];
  __shared__ unsigned short Bs[BN][LDK];
  __shared__ float esl[64][2];
  __shared__ float edl[64][2];
  const int tid = threadIdx.x;
  const int wave = tid >> 6;
  const int lane = tid & 63;
  const int quad = lane >> 4;
  const int l16 = lane & 15;
  const int wrow = wave >> 1;  // 0..1
  const int wcol = wave & 1;   // 0..1
  const int row0 = blockIdx.x * 64;

  f32x4 acc[2][NT] = {};

  for (int k0 = 0; k0 < KTOT; k0 += 64) {
#pragma unroll
    for (int p = 0; p < 4; p++) {
      int m = p * 16 + (tid >> 4);
      int k4 = (tid & 15) * 4;
      int gr = row0 + m;
      uint2 pk = make_uint2(0u, 0u);
      if (gr < M) {
        if (A_BF16) {
          pk = *(const uint2*)((const unsigned short*)Aptr + (size_t)gr * KTOT + k0 + k4);
        } else {
          float4 v = *(const float4*)((const float*)Aptr + (size_t)gr * KTOT + k0 + k4);
          pk.x = (unsigned int)f2bf(v.x) | ((unsigned int)f2bf(v.y) << 16);
          pk.y = (unsigned int)f2bf(v.z) | ((unsigned int)f2bf(v.w) << 16);
        }
      }
      *(uint2*)&As[m][k4] = pk;
    }
#pragma unroll
    for (int p = 0; p < BN / 32; p++) {
      int n = p * 32 + (tid >> 3);
      int k8 = (tid & 7) * 8;
      *(uint4*)&Bs[n][k8] = *(const uint4*)(BT + (size_t)n * KTOT + k0 + k8);
    }
    __syncthreads();
#pragma unroll
    for (int ks = 0; ks < 2; ks++) {
      bf16x8 afrag[2];
#pragma unroll
      for (int rt = 0; rt < 2; rt++)
        afrag[rt] = *(const bf16x8*)&As[wrow * 32 + rt * 16 + l16][ks * 32 + quad * 8];
#pragma unroll
      for (int ct = 0; ct < NT; ct++) {
        bf16x8 bfrag = *(const bf16x8*)&Bs[wcol * CN + ct * 16 + l16][ks * 32 + quad * 8];
#pragma unroll
        for (int rt = 0; rt < 2; rt++)
          acc[rt][ct] = __builtin_amdgcn_mfma_f32_16x16x32_bf16(afrag[rt], bfrag, acc[rt][ct], 0, 0, 0);
      }
    }
    __syncthreads();
  }

  float asv[NT], adv[NT];
#pragma unroll
  for (int ct = 0; ct < NT; ct++) {
    asv[ct] = a_s[wcol * CN + ct * 16 + l16];
    adv[ct] = a_d[wcol * CN + ct * 16 + l16];
  }
#pragma unroll
  for (int rt = 0; rt < 2; rt++) {
#pragma unroll
    for (int r = 0; r < 4; r++) {
      int lrow = wrow * 32 + rt * 16 + quad * 4 + r;
      int grow = row0 + lrow;
      bool ok = (grow < M);
      float ps = 0.f, pd = 0.f;
#pragma unroll
      for (int ct = 0; ct < NT; ct++) {
        float v = acc[rt][ct][r];
        ps += v * asv[ct];
        pd += v * adv[ct];
        if (ok) {
          size_t cidx = (size_t)grow * BN + wcol * CN + ct * 16 + l16;
          if (C_FP8) ((unsigned char*)Cptr)[cidx] = f2fp8(v);
          else       ((unsigned short*)Cptr)[cidx] = f2bf(v);
        }
      }
#pragma unroll
      for (int off = 1; off < 16; off <<= 1) {
        ps += __shfl_xor(ps, off, 16);
        pd += __shfl_xor(pd, off, 16);
      }
      if (l16 == 0) {
        esl[lrow][wcol] = ps;
        edl[lrow][wcol] = pd;
      }
    }
  }
  __syncthreads();
  if (tid < 64) {
    int grow = row0 + tid;
    if (grow < M) {
      es[grow] = esl[tid][0] + esl[tid][1];
      ed[grow] = edl[tid][0] + edl[tid][1];
    }
  }
}

// ---------------- fused softmax+agg, one node per 64-lane wave, fp8 h rows (F=256) ----------------
// Masked constant-depth batches: always 8 row-gathers in flight (clamped index,
// zeroed weight) — no serial tail chain. (src, weight) via readlane (SGPR, uniform).
__global__ __launch_bounds__(256)
void fused_agg64(const int* __restrict__ row_ptr, const int* __restrict__ ssrc,
                 const float* __restrict__ es, const float* __restrict__ ed,
                 const unsigned char* __restrict__ h, const float* __restrict__ bias,
                 unsigned short* __restrict__ outp, int n) {
  int i = blockIdx.x * 4 + (threadIdx.x >> 6);
  int lane = threadIdx.x & 63;
  if (i >= n) return;
  int s = row_ptr[i], e = row_ptr[i + 1];
  int deg = e - s;
  float edv = ed[i];

  // phase 1: chunk-0 logits cached; extra chunks (deg>64: ~never) for max
  int msrc0 = 0;
  float logit0 = -1e30f;
  if (lane < deg) {
    msrc0 = ssrc[s + lane];
    float t = es[msrc0] + edv;
    logit0 = (t > 0.f) ? t : 0.2f * t;
  }
  float mloc = logit0;
  for (int p0 = s + 64; p0 < e; p0 += 64) {
    int p = p0 + lane;
    if (p < e) {
      int ms = ssrc[p];
      float t = es[ms] + edv;
      float lg = (t > 0.f) ? t : 0.2f * t;
      mloc = fmaxf(mloc, lg);
    }
  }
#pragma unroll
  for (int off = 32; off; off >>= 1) mloc = fmaxf(mloc, __shfl_xor(mloc, off, 64));

  // phase 2: exp + accumulate, masked 8-deep batches
  float pv = (lane < deg) ? __expf(logit0 - mloc) : 0.f;
  float lsum = pv;
  unsigned int pvu = __float_as_uint(pv);
  float acc0 = 0.f, acc1 = 0.f, acc2 = 0.f, acc3 = 0.f;
  const unsigned char* hb = h + lane * 4;  // 4 fp8 per lane, 256 B per row-load
  int cnt0 = min(deg, 64);
  for (int j = 0; j < cnt0; j += 8) {
    unsigned int r[8];
    float w[8];
#pragma unroll
    for (int u = 0; u < 8; u++) {
      int jj = j + u;
      bool ok = jj < cnt0;
      int jc = ok ? jj : 0;
      int sj = __builtin_amdgcn_readlane(msrc0, jc);
      float wr = __uint_as_float(__builtin_amdgcn_readlane(pvu, jc));
      w[u] = ok ? wr : 0.f;
      r[u] = *(const unsigned int*)(hb + (size_t)sj * HD);
    }
#pragma unroll
    for (int u = 0; u < 8; u++) {
      f32x2 lo = __builtin_amdgcn_cvt_pk_f32_fp8(r[u], false);
      f32x2 hi = __builtin_amdgcn_cvt_pk_f32_fp8(r[u], true);
      acc0 += w[u] * lo.x;
      acc1 += w[u] * lo.y;
      acc2 += w[u] * hi.x;
      acc3 += w[u] * hi.y;
    }
  }
  // rare: deg > 64
  for (int p0 = s + 64; p0 < e; p0 += 64) {
    int p = p0 + lane;
    int ms = 0;
    float lg = -1e30f;
    if (p < e) {
      ms = ssrc[p];
      float t = es[ms] + edv;
      lg = (t > 0.f) ? t : 0.2f * t;
    }
    float pvc = (p < e) ? __expf(lg - mloc) : 0.f;
    lsum += pvc;
    unsigned int pvcu = __float_as_uint(pvc);
    int cnt = min(64, e - p0);
    for (int jj = 0; jj < cnt; jj++) {
      int sj = __builtin_amdgcn_readlane(ms, jj);
      float wj = __uint_as_float(__builtin_amdgcn_readlane(pvcu, jj));
      unsigned int rv = *(const unsigned int*)(hb + (size_t)sj * HD);
      f32x2 lo = __builtin_amdgcn_cvt_pk_f32_fp8(rv, false);
      f32x2 hi = __builtin_amdgcn_cvt_pk_f32_fp8(rv, true);
      acc0 += wj * lo.x;
      acc1 += wj * lo.y;
      acc2 += wj * hi.x;
      acc3 += wj * hi.y;
    }
  }
#pragma unroll
  for (int off = 32; off; off >>= 1) lsum += __shfl_xor(lsum, off, 64);
  float invd = 1.0f / lsum;
  float4 b4 = *(const float4*)(bias + lane * 4);
  float r0 = fmaxf(acc0 * invd + b4.x, 0.f);   // relu (layer 1 only)
  float r1 = fmaxf(acc1 * invd + b4.y, 0.f);
  float r2 = fmaxf(acc2 * invd + b4.z, 0.f);
  float r3 = fmaxf(acc3 * invd + b4.w, 0.f);
  uint2 pk;
  pk.x = (unsigned int)f2bf(r0) | ((unsigned int)f2bf(r1) << 16);
  pk.y = (unsigned int)f2bf(r2) | ((unsigned int)f2bf(r3) << 16);
  *(uint2*)(outp + (size_t)i * HD + lane * 4) = pk;
}

// ---------------- layer-2 fused agg (32 lanes/node, masked list, bf16 h2, fp32 out) ----------------
// Masked 8-deep batches via __shfl width 32.
__global__ __launch_bounds__(256)
void fused_agg_l2(const int* __restrict__ row_ptr, const int* __restrict__ ssrc,
                  const float* __restrict__ es, const float* __restrict__ ed,
                  const unsigned short* __restrict__ h, const float* __restrict__ bias,
                  float* __restrict__ outp, const int* __restrict__ node_list,
                  const int* __restrict__ node_cnt) {
  constexpr int F = FIN;
  int idx = blockIdx.x * 8 + (threadIdx.x >> 5);
  int ls = threadIdx.x & 31;
  if (idx >= *node_cnt) return;
  int i = node_list[idx];
  int s = row_ptr[i], e = row_ptr[i + 1];
  float edv = ed[i];

  int msrc0 = 0;
  float logit0 = -1e30f;
  {
    int p = s + ls;
    if (p < e) {
      msrc0 = ssrc[p];
      float t = es[msrc0] + edv;
      logit0 = (t > 0.f) ? t : 0.2f * t;
    }
  }
  float M = logit0;
  for (int p0 = s + 32; p0 < e; p0 += 32) {
    int p = p0 + ls;
    if (p < e) {
      int ms = ssrc[p];
      float t = es[ms] + edv;
      float lg = (t > 0.f) ? t : 0.2f * t;
      M = fmaxf(M, lg);
    }
  }
#pragma unroll
  for (int off = 16; off; off >>= 1) M = fmaxf(M, __shfl_xor(M, off, 32));

  float acc[4] = {};
  float lsum = 0.f;
  const unsigned short* hb = h + ls * 4;
  for (int p0 = s; p0 < e; p0 += 32) {
    int msrc;
    float logit;
    if (p0 == s) {
      msrc = msrc0;
      logit = logit0;
    } else {
      int p = p0 + ls;
      msrc = 0;
      logit = -1e30f;
      if (p < e) {
        msrc = ssrc[p];
        float t = es[msrc] + edv;
        logit = (t > 0.f) ? t : 0.2f * t;
      }
    }
    float pv = __expf(logit - M);
    lsum += pv;
    int cnt = min(32, e - p0);
    for (int j = 0; j < cnt; j += 8) {
      uint2 r[8];
      float w[8];
#pragma unroll
      for (int u = 0; u < 8; u++) {
        int jj = j + u;
        bool ok = jj < cnt;
        int jc = ok ? jj : 0;
        int sj = __shfl(msrc, jc, 32);
        float wr = __shfl(pv, jc, 32);
        w[u] = ok ? wr : 0.f;
        r[u] = *(const uint2*)(hb + (size_t)sj * F);
      }
#pragma unroll
      for (int u = 0; u < 8; u++) {
        acc[0] += w[u] * bflo(r[u].x);
        acc[1] += w[u] * bfhi(r[u].x);
        acc[2] += w[u] * bflo(r[u].y);
        acc[3] += w[u] * bfhi(r[u].y);
      }
    }
  }
#pragma unroll
  for (int off = 16; off; off >>= 1) lsum += __shfl_xor(lsum, off, 32);
  float invd = 1.0f / lsum;
  float4 b4 = *(const float4*)(bias + ls * 4);
  float4 r;
  r.x = acc[0] * invd + b4.x;
  r.y = acc[1] * invd + b4.y;
  r.z = acc[2] * invd + b4.z;
  r.w = acc[3] * invd + b4.w;
  *(float4*)(outp + (size_t)i * F + ls * 4) = r;
}

// ---------------- link predictor (one wave per pair, float2 per lane) ----------------
__global__ void predict_kernel(const float* __restrict__ h2, const int* __restrict__ mask,
                               const float* __restrict__ Wl, const float* __restrict__ bl,
                               float* __restrict__ out, int P) {
  int wid = (blockIdx.x * blockDim.x + threadIdx.x) >> 6;
  int lane = threadIdx.x & 63;
  if (wid >= P) return;
  int m0 = mask[wid * 2 + 0];
  int m1 = mask[wid * 2 + 1];
  float2 x0 = *(const float2*)(h2 + (size_t)m0 * FIN + lane * 2);
  float2 x1 = *(const float2*)(h2 + (size_t)m1 * FIN + lane * 2);
  float2 w0 = *(const float2*)(Wl + lane * 2);
  float2 w1 = *(const float2*)(Wl + FIN + lane * 2);
  float s = x0.x * w0.x + x0.y * w0.y + x1.x * w1.x + x1.y * w1.y;
#pragma unroll
  for (int off = 32; off; off >>= 1) s += __shfl_down(s, off);
  if (lane == 0) {
    float z = s + bl[0];
    out[wid] = 1.0f / (1.0f + expf(-z));
  }
}

extern "C" void kernel_launch(void* const* d_in, const int* in_sizes, int n_in,
                              void* d_out, int out_size, void* d_ws, size_t ws_size,
                              hipStream_t stream) {
  const float* features = (const float*)d_in[0];
  const int* edge_index = (const int*)d_in[1];
  const int* mask       = (const int*)d_in[2];
  const float* W1     = (const float*)d_in[3];
  const float* a_src1 = (const float*)d_in[4];
  const float* a_dst1 = (const float*)d_in[5];
  const float* b1     = (const float*)d_in[6];
  const float* W2     = (const float*)d_in[7];
  const float* a_src2 = (const float*)d_in[8];
  const float* a_dst2 = (const float*)d_in[9];
  const float* b2     = (const float*)d_in[10];
  const float* Wl     = (const float*)d_in[11];
  const float* bl     = (const float*)d_in[12];
  float* out = (float*)d_out;

  const int* src = edge_index;        // [E]
  const int* dst = edge_index + NE;   // [E]

  // ---- workspace layout ----
  char* ws = (char*)d_ws;
  size_t off = 0;
  auto alloc = [&](size_t bytes) {
    void* p = ws + off;
    off += (bytes + 255) & ~(size_t)255;
    return p;
  };
  unsigned char* h1q = (unsigned char*)alloc((size_t)NN * HD);            // h1 fp8 (gather rows)
  unsigned short* h2b = (unsigned short*)alloc((size_t)NN * FIN * 2);     // h2 bf16
  unsigned short* x2b = (unsigned short*)alloc((size_t)NN * HD * 2);      // relu(out1) bf16
  float* out2    = (float*)alloc((size_t)NN * FIN * 4);                   // layer2 agg out fp32
  unsigned short* W1T = (unsigned short*)alloc((size_t)HD * FIN * 2);     // [256][128]
  unsigned short* W2T = (unsigned short*)alloc((size_t)FIN * HD * 2);     // [128][256]
  float* es_buf  = (float*)alloc((size_t)NN * 4);
  float* ed_buf  = (float*)alloc((size_t)NN * 4);
  int* deg       = (int*)alloc((size_t)NN * 4);
  int* row_ptr   = (int*)alloc((size_t)(NN + 1) * 4);
  int* cursor    = (int*)alloc((size_t)NN * 4);
  int* ssrc      = (int*)alloc((size_t)NE_TOT * 4);
  int* flags     = (int*)alloc((size_t)NN * 4);
  int* node_list = (int*)alloc((size_t)NN * 4);
  int* node_cnt  = (int*)alloc(256);
  (void)ws_size; (void)in_sizes; (void)n_in; (void)out_size;

  const int nblk_gemm = (NN + 63) / 64;  // 782
  // init_prep must cover max(NN, FIN*HD) = 50000 -> 196 blocks (R9 bug: only covered 33024)
  const int nblk_init = (NN + 255) / 256;  // 196; NN > FIN*HD=32768

  // 1) init + weight prep
  init_prep<<<nblk_init, 256, 0, stream>>>(deg, flags, node_cnt, W1, W2, W1T, W2T);
  // 2) degree histogram + mask flags
  hist_flag<<<(NE + 2 * NP + 255) / 256, 256, 0, stream>>>(dst, deg, mask, flags);
  // 3) scan + compact (single block)
  scan_compact<<<1, 1024, 0, stream>>>(deg, row_ptr, cursor, flags, node_list, node_cnt);
  // 4) CSR scatter
  scatter_kernel<<<(NE_TOT + 255) / 256, 256, 0, stream>>>(src, dst, cursor, ssrc);

  // 5) layer 1 GEMM: h1 = X @ W1 (MFMA bf16, C in fp8) + fused es/ed
  mfma_gemm<HD, FIN, false, true><<<nblk_gemm, 256, 0, stream>>>(
      (const void*)features, W1T, (void*)h1q, a_src1, a_dst1, es_buf, ed_buf, NN);
  // 6) fused softmax + aggregation (all nodes), fp8 gather, bf16 out + relu
  fused_agg64<<<(NN + 3) / 4, 256, 0, stream>>>(
      row_ptr, ssrc, es_buf, ed_buf, h1q, b1, x2b, NN);

  // 7) layer 2 GEMM: h2 = x2 @ W2 (MFMA bf16, C in bf16) + fused es/ed
  mfma_gemm<FIN, HD, true, false><<<nblk_gemm, 256, 0, stream>>>(
      (const void*)x2b, W2T, (void*)h2b, a_src2, a_dst2, es_buf, ed_buf, NN);
  // 8) fused agg restricted to masked dst nodes, fp32 out
  fused_agg_l2<<<(2 * NP + 7) / 8, 256, 0, stream>>>(
      row_ptr, ssrc, es_buf, ed_buf, h2b, b2, out2, node_list, node_cnt);

  // 9) link predictor
  predict_kernel<<<(NP * 64 + 255) / 256, 256, 0, stream>>>(out2, mask, Wl, bl, out, NP);
}

// Round 11
// 241.336 us; speedup vs baseline: 1.6098x; 1.6098x over previous
//
#include <hip/hip_runtime.h>
#include <hip/hip_bf16.h>
#include <math.h>

#define NN 50000      // nodes
#define NE 500000     // edges (before self loops)
#define NP 10000      // pairs
#define FIN 128
#define HD 256
#define NE_TOT (NE + NN)   // with self loops

typedef __attribute__((ext_vector_type(8))) short bf16x8;
typedef __attribute__((ext_vector_type(4))) float f32x4;
typedef __attribute__((ext_vector_type(2))) float f32x2;

// round-to-nearest-even fp32 -> bf16 bits
__device__ inline unsigned short f2bf(float f) {
  unsigned int u = __float_as_uint(f);
  unsigned int r = (u + 0x7fffu + ((u >> 16) & 1u)) >> 16;
  return (unsigned short)r;
}

__device__ inline float bflo(unsigned int u) { return __uint_as_float(u << 16); }
__device__ inline float bfhi(unsigned int u) { return __uint_as_float(u & 0xffff0000u); }

// fp8 e4m3 encode (HW, RNE): one float -> one byte
__device__ inline unsigned char f2fp8(float v) {
  int pk = __builtin_amdgcn_cvt_pk_fp8_f32(v, v, 0, false);
  return (unsigned char)(pk & 0xff);
}

// ---------------- merged init: deg=1, flags=0, cnt=0, weight transpose+convert ----------------
// Launched with 196 blocks x 256 = 50176 >= max(NN=50000, FIN*HD=32768).
__global__ void init_prep(int* __restrict__ deg, int* __restrict__ flags, int* __restrict__ node_cnt,
                          const float* __restrict__ W1, const float* __restrict__ W2,
                          unsigned short* __restrict__ W1T, unsigned short* __restrict__ W2T) {
  int idx = blockIdx.x * 256 + threadIdx.x;
  if (idx < NN) { deg[idx] = 1; flags[idx] = 0; }
  if (idx == 0) *node_cnt = 0;
  if (idx < FIN * HD) {
    int n = idx / FIN, k = idx - n * FIN;
    W1T[idx] = f2bf(W1[(size_t)k * HD + n]);
    int n2 = idx / HD, k2 = idx - n2 * HD;
    W2T[idx] = f2bf(W2[(size_t)k2 * FIN + n2]);
  }
}

// ---------------- merged histogram + mask-flag ----------------
__global__ void hist_flag(const int* __restrict__ dst, int* __restrict__ deg,
                          const int* __restrict__ mask, int* __restrict__ flags) {
  int e = blockIdx.x * blockDim.x + threadIdx.x;
  if (e < NE) atomicAdd(&deg[dst[e]], 1);
  else if (e < NE + 2 * NP) flags[mask[e - NE]] = 1;
}

// ---------------- multi-block 3-phase scan (R8-proven, ~1-3 us each) ----------------
__global__ void scan_phase1(const int* __restrict__ deg, int* __restrict__ incl,
                            int* __restrict__ bsum, int n) {
  __shared__ int tmp[256];
  int i = blockIdx.x * 256 + threadIdx.x;
  int v = (i < n) ? deg[i] : 0;
  tmp[threadIdx.x] = v;
  __syncthreads();
  for (int off = 1; off < 256; off <<= 1) {
    int t = (threadIdx.x >= off) ? tmp[threadIdx.x - off] : 0;
    __syncthreads();
    tmp[threadIdx.x] += t;
    __syncthreads();
  }
  if (i < n) incl[i] = tmp[threadIdx.x];
  if (threadIdx.x == 255) bsum[blockIdx.x] = tmp[255];
}

__global__ void scan_phase2(int* __restrict__ bsum, int nb) {
  __shared__ int tmp[256];
  int v = (threadIdx.x < nb) ? bsum[threadIdx.x] : 0;
  tmp[threadIdx.x] = v;
  __syncthreads();
  for (int off = 1; off < 256; off <<= 1) {
    int t = (threadIdx.x >= off) ? tmp[threadIdx.x - off] : 0;
    __syncthreads();
    tmp[threadIdx.x] += t;
    __syncthreads();
  }
  if (threadIdx.x < nb) bsum[threadIdx.x] = tmp[threadIdx.x] - v;  // exclusive
}

// phase3 + compact merged (both are per-node elementwise)
__global__ void scan_phase3_compact(const int* __restrict__ deg, const int* __restrict__ incl,
                                    const int* __restrict__ bsum, int* __restrict__ row_ptr,
                                    int* __restrict__ cursor, const int* __restrict__ flags,
                                    int* __restrict__ node_list, int* __restrict__ node_cnt,
                                    int n, int total) {
  int i = blockIdx.x * 256 + threadIdx.x;
  if (i < n) {
    int excl = incl[i] - deg[i] + bsum[blockIdx.x];
    row_ptr[i] = excl;
    cursor[i] = excl;
    if (flags[i]) {
      int p = atomicAdd(node_cnt, 1);
      node_list[p] = i;
    }
  }
  if (i == n) row_ptr[n] = total;
}

__global__ void scatter_kernel(const int* __restrict__ src, const int* __restrict__ dst,
                               int* __restrict__ cursor, int* __restrict__ ssrc) {
  int e = blockIdx.x * blockDim.x + threadIdx.x;
  if (e < NE) {
    int pos = atomicAdd(&cursor[dst[e]], 1);
    ssrc[pos] = src[e];
  } else if (e < NE_TOT) {
    int i = e - NE;
    int pos = atomicAdd(&cursor[i], 1);
    ssrc[pos] = i;
  }
}

// ---------------- bf16 MFMA GEMM + fused es/ed epilogue (LDS reduce, plain store) ----------------
// C[M,BN] = A[M,KTOT] @ B[KTOT,BN]; BT is B^T bf16 [BN][KTOT].
// C stored fp8-e4m3 (C_FP8) or bf16. es/ed from fp32 accumulators (exact).
template <int BN, int KTOT, bool A_BF16, bool C_FP8>
__global__ __launch_bounds__(256)
void mfma_gemm(const void* __restrict__ Aptr, const unsigned short* __restrict__ BT,
               void* __restrict__ Cptr, const float* __restrict__ a_s,
               const float* __restrict__ a_d, float* __restrict__ es, float* __restrict__ ed,
               int M) {
  constexpr int LDK = 72;
  constexpr int CN = BN / 2;   // cols per wave
  constexpr int NT = CN / 16;  // 16x16 col tiles per wave
  __shared__ unsigned short As[64][LDK];
  __shared__ unsigned short Bs[BN][LDK];
  __shared__ float esl[64][2];
  __shared__ float edl[64][2];
  const int tid = threadIdx.x;
  const int wave = tid >> 6;
  const int lane = tid & 63;
  const int quad = lane >> 4;
  const int l16 = lane & 15;
  const int wrow = wave >> 1;  // 0..1
  const int wcol = wave & 1;   // 0..1
  const int row0 = blockIdx.x * 64;

  f32x4 acc[2][NT] = {};

  for (int k0 = 0; k0 < KTOT; k0 += 64) {
#pragma unroll
    for (int p = 0; p < 4; p++) {
      int m = p * 16 + (tid >> 4);
      int k4 = (tid & 15) * 4;
      int gr = row0 + m;
      uint2 pk = make_uint2(0u, 0u);
      if (gr < M) {
        if (A_BF16) {
          pk = *(const uint2*)((const unsigned short*)Aptr + (size_t)gr * KTOT + k0 + k4);
        } else {
          float4 v = *(const float4*)((const float*)Aptr + (size_t)gr * KTOT + k0 + k4);
          pk.x = (unsigned int)f2bf(v.x) | ((unsigned int)f2bf(v.y) << 16);
          pk.y = (unsigned int)f2bf(v.z) | ((unsigned int)f2bf(v.w) << 16);
        }
      }
      *(uint2*)&As[m][k4] = pk;
    }
#pragma unroll
    for (int p = 0; p < BN / 32; p++) {
      int n = p * 32 + (tid >> 3);
      int k8 = (tid & 7) * 8;
      *(uint4*)&Bs[n][k8] = *(const uint4*)(BT + (size_t)n * KTOT + k0 + k8);
    }
    __syncthreads();
#pragma unroll
    for (int ks = 0; ks < 2; ks++) {
      bf16x8 afrag[2];
#pragma unroll
      for (int rt = 0; rt < 2; rt++)
        afrag[rt] = *(const bf16x8*)&As[wrow * 32 + rt * 16 + l16][ks * 32 + quad * 8];
#pragma unroll
      for (int ct = 0; ct < NT; ct++) {
        bf16x8 bfrag = *(const bf16x8*)&Bs[wcol * CN + ct * 16 + l16][ks * 32 + quad * 8];
#pragma unroll
        for (int rt = 0; rt < 2; rt++)
          acc[rt][ct] = __builtin_amdgcn_mfma_f32_16x16x32_bf16(afrag[rt], bfrag, acc[rt][ct], 0, 0, 0);
      }
    }
    __syncthreads();
  }

  float asv[NT], adv[NT];
#pragma unroll
  for (int ct = 0; ct < NT; ct++) {
    asv[ct] = a_s[wcol * CN + ct * 16 + l16];
    adv[ct] = a_d[wcol * CN + ct * 16 + l16];
  }
#pragma unroll
  for (int rt = 0; rt < 2; rt++) {
#pragma unroll
    for (int r = 0; r < 4; r++) {
      int lrow = wrow * 32 + rt * 16 + quad * 4 + r;
      int grow = row0 + lrow;
      bool ok = (grow < M);
      float ps = 0.f, pd = 0.f;
#pragma unroll
      for (int ct = 0; ct < NT; ct++) {
        float v = acc[rt][ct][r];
        ps += v * asv[ct];
        pd += v * adv[ct];
        if (ok) {
          size_t cidx = (size_t)grow * BN + wcol * CN + ct * 16 + l16;
          if (C_FP8) ((unsigned char*)Cptr)[cidx] = f2fp8(v);
          else       ((unsigned short*)Cptr)[cidx] = f2bf(v);
        }
      }
#pragma unroll
      for (int off = 1; off < 16; off <<= 1) {
        ps += __shfl_xor(ps, off, 16);
        pd += __shfl_xor(pd, off, 16);
      }
      if (l16 == 0) {
        esl[lrow][wcol] = ps;
        edl[lrow][wcol] = pd;
      }
    }
  }
  __syncthreads();
  if (tid < 64) {
    int grow = row0 + tid;
    if (grow < M) {
      es[grow] = esl[tid][0] + esl[tid][1];
      ed[grow] = edl[tid][0] + edl[tid][1];
    }
  }
}

// ---------------- fused softmax+agg, one node per 64-lane wave, fp8 h rows (F=256) ----------------
// Masked constant-depth batches: always 8 row-gathers in flight (clamped index,
// zeroed weight) — no serial tail chain. (src, weight) via readlane (SGPR, uniform).
__global__ __launch_bounds__(256)
void fused_agg64(const int* __restrict__ row_ptr, const int* __restrict__ ssrc,
                 const float* __restrict__ es, const float* __restrict__ ed,
                 const unsigned char* __restrict__ h, const float* __restrict__ bias,
                 unsigned short* __restrict__ outp, int n) {
  int i = blockIdx.x * 4 + (threadIdx.x >> 6);
  int lane = threadIdx.x & 63;
  if (i >= n) return;
  int s = row_ptr[i], e = row_ptr[i + 1];
  int deg = e - s;
  float edv = ed[i];

  // phase 1: chunk-0 logits cached; extra chunks (deg>64: ~never) for max
  int msrc0 = 0;
  float logit0 = -1e30f;
  if (lane < deg) {
    msrc0 = ssrc[s + lane];
    float t = es[msrc0] + edv;
    logit0 = (t > 0.f) ? t : 0.2f * t;
  }
  float mloc = logit0;
  for (int p0 = s + 64; p0 < e; p0 += 64) {
    int p = p0 + lane;
    if (p < e) {
      int ms = ssrc[p];
      float t = es[ms] + edv;
      float lg = (t > 0.f) ? t : 0.2f * t;
      mloc = fmaxf(mloc, lg);
    }
  }
#pragma unroll
  for (int off = 32; off; off >>= 1) mloc = fmaxf(mloc, __shfl_xor(mloc, off, 64));

  // phase 2: exp + accumulate, masked 8-deep batches
  float pv = (lane < deg) ? __expf(logit0 - mloc) : 0.f;
  float lsum = pv;
  unsigned int pvu = __float_as_uint(pv);
  float acc0 = 0.f, acc1 = 0.f, acc2 = 0.f, acc3 = 0.f;
  const unsigned char* hb = h + lane * 4;  // 4 fp8 per lane, 256 B per row-load
  int cnt0 = min(deg, 64);
  for (int j = 0; j < cnt0; j += 8) {
    unsigned int r[8];
    float w[8];
#pragma unroll
    for (int u = 0; u < 8; u++) {
      int jj = j + u;
      bool ok = jj < cnt0;
      int jc = ok ? jj : 0;
      int sj = __builtin_amdgcn_readlane(msrc0, jc);
      float wr = __uint_as_float(__builtin_amdgcn_readlane(pvu, jc));
      w[u] = ok ? wr : 0.f;
      r[u] = *(const unsigned int*)(hb + (size_t)sj * HD);
    }
#pragma unroll
    for (int u = 0; u < 8; u++) {
      f32x2 lo = __builtin_amdgcn_cvt_pk_f32_fp8(r[u], false);
      f32x2 hi = __builtin_amdgcn_cvt_pk_f32_fp8(r[u], true);
      acc0 += w[u] * lo.x;
      acc1 += w[u] * lo.y;
      acc2 += w[u] * hi.x;
      acc3 += w[u] * hi.y;
    }
  }
  // rare: deg > 64
  for (int p0 = s + 64; p0 < e; p0 += 64) {
    int p = p0 + lane;
    int ms = 0;
    float lg = -1e30f;
    if (p < e) {
      ms = ssrc[p];
      float t = es[ms] + edv;
      lg = (t > 0.f) ? t : 0.2f * t;
    }
    float pvc = (p < e) ? __expf(lg - mloc) : 0.f;
    lsum += pvc;
    unsigned int pvcu = __float_as_uint(pvc);
    int cnt = min(64, e - p0);
    for (int jj = 0; jj < cnt; jj++) {
      int sj = __builtin_amdgcn_readlane(ms, jj);
      float wj = __uint_as_float(__builtin_amdgcn_readlane(pvcu, jj));
      unsigned int rv = *(const unsigned int*)(hb + (size_t)sj * HD);
      f32x2 lo = __builtin_amdgcn_cvt_pk_f32_fp8(rv, false);
      f32x2 hi = __builtin_amdgcn_cvt_pk_f32_fp8(rv, true);
      acc0 += wj * lo.x;
      acc1 += wj * lo.y;
      acc2 += wj * hi.x;
      acc3 += wj * hi.y;
    }
  }
#pragma unroll
  for (int off = 32; off; off >>= 1) lsum += __shfl_xor(lsum, off, 64);
  float invd = 1.0f / lsum;
  float4 b4 = *(const float4*)(bias + lane * 4);
  float r0 = fmaxf(acc0 * invd + b4.x, 0.f);   // relu (layer 1 only)
  float r1 = fmaxf(acc1 * invd + b4.y, 0.f);
  float r2 = fmaxf(acc2 * invd + b4.z, 0.f);
  float r3 = fmaxf(acc3 * invd + b4.w, 0.f);
  uint2 pk;
  pk.x = (unsigned int)f2bf(r0) | ((unsigned int)f2bf(r1) << 16);
  pk.y = (unsigned int)f2bf(r2) | ((unsigned int)f2bf(r3) << 16);
  *(uint2*)(outp + (size_t)i * HD + lane * 4) = pk;
}

// ---------------- layer-2 fused agg (32 lanes/node, masked list, bf16 h2, fp32 out) ----------------
// Masked 8-deep batches via __shfl width 32.
__global__ __launch_bounds__(256)
void fused_agg_l2(const int* __restrict__ row_ptr, const int* __restrict__ ssrc,
                  const float* __restrict__ es, const float* __restrict__ ed,
                  const unsigned short* __restrict__ h, const float* __restrict__ bias,
                  float* __restrict__ outp, const int* __restrict__ node_list,
                  const int* __restrict__ node_cnt) {
  constexpr int F = FIN;
  int idx = blockIdx.x * 8 + (threadIdx.x >> 5);
  int ls = threadIdx.x & 31;
  if (idx >= *node_cnt) return;
  int i = node_list[idx];
  int s = row_ptr[i], e = row_ptr[i + 1];
  float edv = ed[i];

  int msrc0 = 0;
  float logit0 = -1e30f;
  {
    int p = s + ls;
    if (p < e) {
      msrc0 = ssrc[p];
      float t = es[msrc0] + edv;
      logit0 = (t > 0.f) ? t : 0.2f * t;
    }
  }
  float M = logit0;
  for (int p0 = s + 32; p0 < e; p0 += 32) {
    int p = p0 + ls;
    if (p < e) {
      int ms = ssrc[p];
      float t = es[ms] + edv;
      float lg = (t > 0.f) ? t : 0.2f * t;
      M = fmaxf(M, lg);
    }
  }
#pragma unroll
  for (int off = 16; off; off >>= 1) M = fmaxf(M, __shfl_xor(M, off, 32));

  float acc[4] = {};
  float lsum = 0.f;
  const unsigned short* hb = h + ls * 4;
  for (int p0 = s; p0 < e; p0 += 32) {
    int msrc;
    float logit;
    if (p0 == s) {
      msrc = msrc0;
      logit = logit0;
    } else {
      int p = p0 + ls;
      msrc = 0;
      logit = -1e30f;
      if (p < e) {
        msrc = ssrc[p];
        float t = es[msrc] + edv;
        logit = (t > 0.f) ? t : 0.2f * t;
      }
    }
    float pv = __expf(logit - M);
    lsum += pv;
    int cnt = min(32, e - p0);
    for (int j = 0; j < cnt; j += 8) {
      uint2 r[8];
      float w[8];
#pragma unroll
      for (int u = 0; u < 8; u++) {
        int jj = j + u;
        bool ok = jj < cnt;
        int jc = ok ? jj : 0;
        int sj = __shfl(msrc, jc, 32);
        float wr = __shfl(pv, jc, 32);
        w[u] = ok ? wr : 0.f;
        r[u] = *(const uint2*)(hb + (size_t)sj * F);
      }
#pragma unroll
      for (int u = 0; u < 8; u++) {
        acc[0] += w[u] * bflo(r[u].x);
        acc[1] += w[u] * bfhi(r[u].x);
        acc[2] += w[u] * bflo(r[u].y);
        acc[3] += w[u] * bfhi(r[u].y);
      }
    }
  }
#pragma unroll
  for (int off = 16; off; off >>= 1) lsum += __shfl_xor(lsum, off, 32);
  float invd = 1.0f / lsum;
  float4 b4 = *(const float4*)(bias + ls * 4);
  float4 r;
  r.x = acc[0] * invd + b4.x;
  r.y = acc[1] * invd + b4.y;
  r.z = acc[2] * invd + b4.z;
  r.w = acc[3] * invd + b4.w;
  *(float4*)(outp + (size_t)i * F + ls * 4) = r;
}

// ---------------- link predictor (one wave per pair, float2 per lane) ----------------
__global__ void predict_kernel(const float* __restrict__ h2, const int* __restrict__ mask,
                               const float* __restrict__ Wl, const float* __restrict__ bl,
                               float* __restrict__ out, int P) {
  int wid = (blockIdx.x * blockDim.x + threadIdx.x) >> 6;
  int lane = threadIdx.x & 63;
  if (wid >= P) return;
  int m0 = mask[wid * 2 + 0];
  int m1 = mask[wid * 2 + 1];
  float2 x0 = *(const float2*)(h2 + (size_t)m0 * FIN + lane * 2);
  float2 x1 = *(const float2*)(h2 + (size_t)m1 * FIN + lane * 2);
  float2 w0 = *(const float2*)(Wl + lane * 2);
  float2 w1 = *(const float2*)(Wl + FIN + lane * 2);
  float s = x0.x * w0.x + x0.y * w0.y + x1.x * w1.x + x1.y * w1.y;
#pragma unroll
  for (int off = 32; off; off >>= 1) s += __shfl_down(s, off);
  if (lane == 0) {
    float z = s + bl[0];
    out[wid] = 1.0f / (1.0f + expf(-z));
  }
}

extern "C" void kernel_launch(void* const* d_in, const int* in_sizes, int n_in,
                              void* d_out, int out_size, void* d_ws, size_t ws_size,
                              hipStream_t stream) {
  const float* features = (const float*)d_in[0];
  const int* edge_index = (const int*)d_in[1];
  const int* mask       = (const int*)d_in[2];
  const float* W1     = (const float*)d_in[3];
  const float* a_src1 = (const float*)d_in[4];
  const float* a_dst1 = (const float*)d_in[5];
  const float* b1     = (const float*)d_in[6];
  const float* W2     = (const float*)d_in[7];
  const float* a_src2 = (const float*)d_in[8];
  const float* a_dst2 = (const float*)d_in[9];
  const float* b2     = (const float*)d_in[10];
  const float* Wl     = (const float*)d_in[11];
  const float* bl     = (const float*)d_in[12];
  float* out = (float*)d_out;

  const int* src = edge_index;        // [E]
  const int* dst = edge_index + NE;   // [E]

  // ---- workspace layout ----
  char* ws = (char*)d_ws;
  size_t off = 0;
  auto alloc = [&](size_t bytes) {
    void* p = ws + off;
    off += (bytes + 255) & ~(size_t)255;
    return p;
  };
  unsigned char* h1q = (unsigned char*)alloc((size_t)NN * HD);            // h1 fp8 (gather rows)
  unsigned short* h2b = (unsigned short*)alloc((size_t)NN * FIN * 2);     // h2 bf16
  unsigned short* x2b = (unsigned short*)alloc((size_t)NN * HD * 2);      // relu(out1) bf16
  float* out2    = (float*)alloc((size_t)NN * FIN * 4);                   // layer2 agg out fp32
  unsigned short* W1T = (unsigned short*)alloc((size_t)HD * FIN * 2);     // [256][128]
  unsigned short* W2T = (unsigned short*)alloc((size_t)FIN * HD * 2);     // [128][256]
  float* es_buf  = (float*)alloc((size_t)NN * 4);
  float* ed_buf  = (float*)alloc((size_t)NN * 4);
  int* deg       = (int*)alloc((size_t)NN * 4);
  int* incl      = (int*)alloc((size_t)NN * 4);
  int* bsum      = (int*)alloc(1024);
  int* row_ptr   = (int*)alloc((size_t)(NN + 1) * 4);
  int* cursor    = (int*)alloc((size_t)NN * 4);
  int* ssrc      = (int*)alloc((size_t)NE_TOT * 4);
  int* flags     = (int*)alloc((size_t)NN * 4);
  int* node_list = (int*)alloc((size_t)NN * 4);
  int* node_cnt  = (int*)alloc(256);
  (void)ws_size; (void)in_sizes; (void)n_in; (void)out_size;

  const int nblk_gemm = (NN + 63) / 64;    // 782
  const int nblk_n256 = (NN + 255) / 256;  // 196 (covers NN and FIN*HD)

  // 1) init + weight prep
  init_prep<<<nblk_n256, 256, 0, stream>>>(deg, flags, node_cnt, W1, W2, W1T, W2T);
  // 2) degree histogram + mask flags
  hist_flag<<<(NE + 2 * NP + 255) / 256, 256, 0, stream>>>(dst, deg, mask, flags);
  // 3-5) multi-block scan + compact (R10's single-block version was 170 us — 1 CU!)
  scan_phase1<<<nblk_n256, 256, 0, stream>>>(deg, incl, bsum, NN);
  scan_phase2<<<1, 256, 0, stream>>>(bsum, nblk_n256);
  scan_phase3_compact<<<nblk_n256 + 1, 256, 0, stream>>>(
      deg, incl, bsum, row_ptr, cursor, flags, node_list, node_cnt, NN, NE_TOT);
  // 6) CSR scatter
  scatter_kernel<<<(NE_TOT + 255) / 256, 256, 0, stream>>>(src, dst, cursor, ssrc);

  // 7) layer 1 GEMM: h1 = X @ W1 (MFMA bf16, C in fp8) + fused es/ed
  mfma_gemm<HD, FIN, false, true><<<nblk_gemm, 256, 0, stream>>>(
      (const void*)features, W1T, (void*)h1q, a_src1, a_dst1, es_buf, ed_buf, NN);
  // 8) fused softmax + aggregation (all nodes), fp8 gather, bf16 out + relu
  fused_agg64<<<(NN + 3) / 4, 256, 0, stream>>>(
      row_ptr, ssrc, es_buf, ed_buf, h1q, b1, x2b, NN);

  // 9) layer 2 GEMM: h2 = x2 @ W2 (MFMA bf16, C in bf16) + fused es/ed
  mfma_gemm<FIN, HD, true, false><<<nblk_gemm, 256, 0, stream>>>(
      (const void*)x2b, W2T, (void*)h2b, a_src2, a_dst2, es_buf, ed_buf, NN);
  // 10) fused agg restricted to masked dst nodes, fp32 out
  fused_agg_l2<<<(2 * NP + 7) / 8, 256, 0, stream>>>(
      row_ptr, ssrc, es_buf, ed_buf, h2b, b2, out2, node_list, node_cnt);

  // 11) link predictor
  predict_kernel<<<(NP * 64 + 255) / 256, 256, 0, stream>>>(out2, mask, Wl, bl, out, NP);
}